// Round 4
// baseline (152.511 us; speedup 1.0000x reference)
//
#include <hip/hip_runtime.h>

// x: (B=4, C=64, H=512, W=512) fp32 -> 131072 independent rows of 512 cols.
// FIR: f[j] = sum_k a[k]*x[j-2+k] (SAME zero-pad), then IIR:
//   y[j] = f[j] - (v0*y[j-3] + v1*y[j-2] + v2*y[j-1]), zero initial state.
//
// thread = (row, 32-col segment); 8 rows x 16 segs = 128 threads/block.
//   phase1: per-segment particular solution y_p (zero entry state), serial 32
//   scan  : in-wave Hillis-Steele affine scan over segments (shuffles, no LDS):
//           b_s <- T^d b_{s-d} + b_s, d=1,2,4,8; entering state = b_{s-1}
//   fixup : y[k] = y_p[k] + Htab[k] . s_enter
// Global I/O coalesced through LDS tile [8][16][9*float4]; drain via dwordx2.

constexpr int Wd     = 512;
constexpr int TROWS  = 8;
constexpr int NT     = 128;
constexpr int SEGS   = 16;
constexpr int SEGP4  = 9;                  // float4 pitch per segment (8 data + 1 pad)
constexpr int ROWP4  = SEGS * SEGP4;       // 144
constexpr int F4ROW  = Wd / 4;             // 128

__global__ __launch_bounds__(NT, 4)
void iir_conv2d_kernel(const float4* __restrict__ x4,
                       const float* __restrict__ w1,   // (C,1,5)
                       const float* __restrict__ w2,   // (C,3)
                       float4* __restrict__ y4)
{
    __shared__ float4 tile[TROWS * ROWP4];   // 18432 B; x then y in place
    __shared__ float  Htab[32][3];           // homogeneous responses
    __shared__ float  TP[3][3][3];           // T^2, T^4, T^8

    const int tid  = threadIdx.x;
    const int lane = tid & 63;
    const int row0 = blockIdx.x * TROWS;     // 8 | 512 -> channel uniform per block
    const int c    = (row0 >> 9) & 63;

    // ---- issue coalesced global loads first (stay in flight under setup) ----
    const float4* __restrict__ xb = x4 + (size_t)row0 * F4ROW;
    float4 st[8];
    #pragma unroll
    for (int it = 0; it < 8; ++it) st[it] = xb[it * NT + tid];

    const float v0 = w2[c*3+0], v1 = w2[c*3+1], v2 = w2[c*3+2];

    // ---- Htab + T powers (thread 0; hidden under load latency) ----
    if (tid == 0) {
        float h3[3] = {1.f, 0.f, 0.f};
        float h2[3] = {0.f, 1.f, 0.f};
        float h1[3] = {0.f, 0.f, 1.f};
        for (int k = 0; k < 32; ++k) {
            #pragma unroll
            for (int j = 0; j < 3; ++j) {
                const float n = -(v0*h3[j] + v1*h2[j] + v2*h1[j]);
                Htab[k][j] = n;
                h3[j] = h2[j]; h2[j] = h1[j]; h1[j] = n;
            }
        }
        float T1[3][3], T2[3][3], T4[3][3];
        #pragma unroll
        for (int i = 0; i < 3; ++i)
            #pragma unroll
            for (int j = 0; j < 3; ++j) T1[i][j] = Htab[29+i][j];
        #pragma unroll
        for (int i = 0; i < 3; ++i)
            #pragma unroll
            for (int j = 0; j < 3; ++j) {
                float acc = 0.f;
                #pragma unroll
                for (int k = 0; k < 3; ++k) acc += T1[i][k]*T1[k][j];
                T2[i][j] = acc; TP[0][i][j] = acc;
            }
        #pragma unroll
        for (int i = 0; i < 3; ++i)
            #pragma unroll
            for (int j = 0; j < 3; ++j) {
                float acc = 0.f;
                #pragma unroll
                for (int k = 0; k < 3; ++k) acc += T2[i][k]*T2[k][j];
                T4[i][j] = acc; TP[1][i][j] = acc;
            }
        #pragma unroll
        for (int i = 0; i < 3; ++i)
            #pragma unroll
            for (int j = 0; j < 3; ++j) {
                float acc = 0.f;
                #pragma unroll
                for (int k = 0; k < 3; ++k) acc += T4[i][k]*T4[k][j];
                TP[2][i][j] = acc;
            }
    }

    // ---- stage x into LDS ----
    #pragma unroll
    for (int it = 0; it < 8; ++it) {
        const int idx = it * NT + tid;
        const int r = idx >> 7, g = idx & 127;
        tile[r * ROWP4 + (g >> 3) * SEGP4 + (g & 7)] = st[it];
    }
    __syncthreads();

    // ---- phase 1: particular solution per segment ----
    const int r = tid >> 4;        // row in tile
    const int s = tid & 15;        // segment
    const float a0 = w1[c*5+0], a1 = w1[c*5+1], a2 = w1[c*5+2],
                a3 = w1[c*5+3], a4 = w1[c*5+4];

    float xfl[40];                 // cols j0-4 .. j0+35
    #pragma unroll
    for (int k = 0; k < 10; ++k) {
        const int g = s * 8 + k - 1;
        const bool valid = (g >= 0) && (g < F4ROW);
        const int gg = valid ? g : 0;
        float4 v = tile[r * ROWP4 + (gg >> 3) * SEGP4 + (gg & 7)];
        if (!valid) { v.x = 0.f; v.y = 0.f; v.z = 0.f; v.w = 0.f; }
        xfl[4*k+0] = v.x; xfl[4*k+1] = v.y; xfl[4*k+2] = v.z; xfl[4*k+3] = v.w;
    }
    float y[32];
    {
        float ym3 = 0.f, ym2 = 0.f, ym1 = 0.f;
        #pragma unroll
        for (int k = 0; k < 32; ++k) {
            const float f = a0*xfl[k+2] + a1*xfl[k+3] + a2*xfl[k+4]
                          + a3*xfl[k+5] + a4*xfl[k+6];
            const float t = v0*ym3 + v1*ym2;      // off the serial chain
            const float yy = (f - t) - v2*ym1;
            y[k] = yy;
            ym3 = ym2; ym2 = ym1; ym1 = yy;
        }
    }

    // ---- affine scan over segments (in-wave, shuffles only) ----
    float b0 = y[29], b1 = y[30], b2 = y[31];
    #pragma unroll
    for (int rd = 0; rd < 4; ++rd) {
        const int d = 1 << rd;
        float t00, t01, t02, t10, t11, t12, t20, t21, t22;
        if (rd == 0) {
            t00 = Htab[29][0]; t01 = Htab[29][1]; t02 = Htab[29][2];
            t10 = Htab[30][0]; t11 = Htab[30][1]; t12 = Htab[30][2];
            t20 = Htab[31][0]; t21 = Htab[31][1]; t22 = Htab[31][2];
        } else {
            t00 = TP[rd-1][0][0]; t01 = TP[rd-1][0][1]; t02 = TP[rd-1][0][2];
            t10 = TP[rd-1][1][0]; t11 = TP[rd-1][1][1]; t12 = TP[rd-1][1][2];
            t20 = TP[rd-1][2][0]; t21 = TP[rd-1][2][1]; t22 = TP[rd-1][2][2];
        }
        const int src = (s >= d) ? (lane - d) : lane;
        const float g0 = __shfl(b0, src, 64);
        const float g1 = __shfl(b1, src, 64);
        const float g2 = __shfl(b2, src, 64);
        if (s >= d) {
            b0 += t00*g0 + t01*g1 + t02*g2;
            b1 += t10*g0 + t11*g1 + t12*g2;
            b2 += t20*g0 + t21*g1 + t22*g2;
        }
    }
    // entering state for this segment = inclusive scan of previous segment
    {
        const int src = (s >= 1) ? (lane - 1) : lane;
        float s0 = __shfl(b0, src, 64);
        float s1 = __shfl(b1, src, 64);
        float s2 = __shfl(b2, src, 64);
        if (s == 0) { s0 = 0.f; s1 = 0.f; s2 = 0.f; }
        #pragma unroll
        for (int k = 0; k < 32; ++k)
            y[k] += Htab[k][0]*s0 + Htab[k][1]*s1 + Htab[k][2]*s2;
    }
    __syncthreads();   // all tile reads (phase 1) complete before overwrite

    // ---- write y into tile (in place) ----
    #pragma unroll
    for (int u = 0; u < 8; ++u) {
        float4 o;
        o.x = y[4*u+0]; o.y = y[4*u+1]; o.z = y[4*u+2]; o.w = y[4*u+3];
        tile[r * ROWP4 + s * SEGP4 + u] = o;
    }
    __syncthreads();

    // ---- drain: contiguous dwordx2 stores (512 B per wave per instr) ----
    const float2* __restrict__ t2 = reinterpret_cast<const float2*>(tile);
    float2* __restrict__ yb2 = reinterpret_cast<float2*>(y4 + (size_t)row0 * F4ROW);
    #pragma unroll
    for (int it = 0; it < 16; ++it) {
        const int idx = it * NT + tid;      // 0..2047 float2
        const int rr = idx >> 8;            // 256 float2 per row
        const int g  = idx & 255;
        yb2[idx] = t2[rr * (ROWP4*2) + (g >> 4) * (SEGP4*2) + (g & 15)];
    }
}

extern "C" void kernel_launch(void* const* d_in, const int* in_sizes, int n_in,
                              void* d_out, int out_size, void* d_ws, size_t ws_size,
                              hipStream_t stream) {
    const float4* x4 = (const float4*)d_in[0];
    const float*  w1 = (const float*)d_in[1];
    const float*  w2 = (const float*)d_in[2];
    float4* y4 = (float4*)d_out;

    const int nrows  = out_size / Wd;        // 131072
    const int blocks = nrows / TROWS;        // 16384
    iir_conv2d_kernel<<<blocks, NT, 0, stream>>>(x4, w1, w2, y4);
}

// Round 5
// 151.550 us; speedup vs baseline: 1.0063x; 1.0063x over previous
//
#include <hip/hip_runtime.h>

// x: (B=4, C=64, H=512, W=512) fp32 -> 131072 independent rows of 512 cols.
// FIR: f[j] = sum_k a[k]*x[j-2+k] (SAME zero-pad), then IIR:
//   y[j] = f[j] - (v0*y[j-3] + v1*y[j-2] + v2*y[j-1]), zero initial state.
//
// thread = (row, 32-col segment); 8 rows x 16 segs = 128 threads/block.
//   phase1: per-segment particular solution y_p (zero entry state), serial 32
//   scan  : in-wave Hillis-Steele affine scan over segments (shuffles, no LDS)
//   fixup : y[k] = y_p[k] + Htab[k] . s_enter
// Drain uses contiguous SCALAR dword stores (empirically the only pattern
// that reports 1x WRITE_SIZE; wide stores measured exactly 2x).

constexpr int Wd     = 512;
constexpr int TROWS  = 8;
constexpr int NT     = 128;
constexpr int SEGS   = 16;
constexpr int SEGP4  = 9;                  // float4 pitch per segment (8 data + 1 pad)
constexpr int ROWP4  = SEGS * SEGP4;       // 144 float4 per row
constexpr int F4ROW  = Wd / 4;             // 128

__global__ __launch_bounds__(NT, 4)
void iir_conv2d_kernel(const float4* __restrict__ x4,
                       const float* __restrict__ w1,   // (C,1,5)
                       const float* __restrict__ w2,   // (C,3)
                       float4* __restrict__ y4)
{
    __shared__ float4 tile[TROWS * ROWP4];   // 18432 B; x then y in place
    __shared__ float  Htab[32][3];           // homogeneous responses
    __shared__ float  TP[3][3][3];           // T^2, T^4, T^8

    const int tid  = threadIdx.x;
    const int lane = tid & 63;
    const int row0 = blockIdx.x * TROWS;     // 8 | 512 -> channel uniform per block
    const int c    = (row0 >> 9) & 63;

    // ---- issue coalesced global loads first (stay in flight under setup) ----
    const float4* __restrict__ xb = x4 + (size_t)row0 * F4ROW;
    float4 st[8];
    #pragma unroll
    for (int it = 0; it < 8; ++it) st[it] = xb[it * NT + tid];

    const float v0 = w2[c*3+0], v1 = w2[c*3+1], v2 = w2[c*3+2];

    // ---- Htab + T powers (thread 0; hidden under load latency) ----
    if (tid == 0) {
        float h3[3] = {1.f, 0.f, 0.f};
        float h2[3] = {0.f, 1.f, 0.f};
        float h1[3] = {0.f, 0.f, 1.f};
        for (int k = 0; k < 32; ++k) {
            #pragma unroll
            for (int j = 0; j < 3; ++j) {
                const float n = -(v0*h3[j] + v1*h2[j] + v2*h1[j]);
                Htab[k][j] = n;
                h3[j] = h2[j]; h2[j] = h1[j]; h1[j] = n;
            }
        }
        float T1[3][3], T2[3][3], T4[3][3];
        #pragma unroll
        for (int i = 0; i < 3; ++i)
            #pragma unroll
            for (int j = 0; j < 3; ++j) T1[i][j] = Htab[29+i][j];
        #pragma unroll
        for (int i = 0; i < 3; ++i)
            #pragma unroll
            for (int j = 0; j < 3; ++j) {
                float acc = 0.f;
                #pragma unroll
                for (int k = 0; k < 3; ++k) acc += T1[i][k]*T1[k][j];
                T2[i][j] = acc; TP[0][i][j] = acc;
            }
        #pragma unroll
        for (int i = 0; i < 3; ++i)
            #pragma unroll
            for (int j = 0; j < 3; ++j) {
                float acc = 0.f;
                #pragma unroll
                for (int k = 0; k < 3; ++k) acc += T2[i][k]*T2[k][j];
                T4[i][j] = acc; TP[1][i][j] = acc;
            }
        #pragma unroll
        for (int i = 0; i < 3; ++i)
            #pragma unroll
            for (int j = 0; j < 3; ++j) {
                float acc = 0.f;
                #pragma unroll
                for (int k = 0; k < 3; ++k) acc += T4[i][k]*T4[k][j];
                TP[2][i][j] = acc;
            }
    }

    // ---- stage x into LDS ----
    #pragma unroll
    for (int it = 0; it < 8; ++it) {
        const int idx = it * NT + tid;
        const int r = idx >> 7, g = idx & 127;
        tile[r * ROWP4 + (g >> 3) * SEGP4 + (g & 7)] = st[it];
    }
    __syncthreads();

    // ---- phase 1: particular solution per segment ----
    const int r = tid >> 4;        // row in tile
    const int s = tid & 15;        // segment
    const float a0 = w1[c*5+0], a1 = w1[c*5+1], a2 = w1[c*5+2],
                a3 = w1[c*5+3], a4 = w1[c*5+4];

    float xfl[40];                 // cols j0-4 .. j0+35
    #pragma unroll
    for (int k = 0; k < 10; ++k) {
        const int g = s * 8 + k - 1;
        const bool valid = (g >= 0) && (g < F4ROW);
        const int gg = valid ? g : 0;
        float4 v = tile[r * ROWP4 + (gg >> 3) * SEGP4 + (gg & 7)];
        if (!valid) { v.x = 0.f; v.y = 0.f; v.z = 0.f; v.w = 0.f; }
        xfl[4*k+0] = v.x; xfl[4*k+1] = v.y; xfl[4*k+2] = v.z; xfl[4*k+3] = v.w;
    }
    float y[32];
    {
        float ym3 = 0.f, ym2 = 0.f, ym1 = 0.f;
        #pragma unroll
        for (int k = 0; k < 32; ++k) {
            const float f = a0*xfl[k+2] + a1*xfl[k+3] + a2*xfl[k+4]
                          + a3*xfl[k+5] + a4*xfl[k+6];
            const float t = v0*ym3 + v1*ym2;      // off the serial chain
            const float yy = (f - t) - v2*ym1;
            y[k] = yy;
            ym3 = ym2; ym2 = ym1; ym1 = yy;
        }
    }

    // ---- affine scan over segments (in-wave, shuffles only) ----
    float b0 = y[29], b1 = y[30], b2 = y[31];
    #pragma unroll
    for (int rd = 0; rd < 4; ++rd) {
        const int d = 1 << rd;
        float t00, t01, t02, t10, t11, t12, t20, t21, t22;
        if (rd == 0) {
            t00 = Htab[29][0]; t01 = Htab[29][1]; t02 = Htab[29][2];
            t10 = Htab[30][0]; t11 = Htab[30][1]; t12 = Htab[30][2];
            t20 = Htab[31][0]; t21 = Htab[31][1]; t22 = Htab[31][2];
        } else {
            t00 = TP[rd-1][0][0]; t01 = TP[rd-1][0][1]; t02 = TP[rd-1][0][2];
            t10 = TP[rd-1][1][0]; t11 = TP[rd-1][1][1]; t12 = TP[rd-1][1][2];
            t20 = TP[rd-1][2][0]; t21 = TP[rd-1][2][1]; t22 = TP[rd-1][2][2];
        }
        const int src = (s >= d) ? (lane - d) : lane;
        const float g0 = __shfl(b0, src, 64);
        const float g1 = __shfl(b1, src, 64);
        const float g2 = __shfl(b2, src, 64);
        if (s >= d) {
            b0 += t00*g0 + t01*g1 + t02*g2;
            b1 += t10*g0 + t11*g1 + t12*g2;
            b2 += t20*g0 + t21*g1 + t22*g2;
        }
    }
    // entering state for this segment = inclusive scan of previous segment
    {
        const int src = (s >= 1) ? (lane - 1) : lane;
        float s0 = __shfl(b0, src, 64);
        float s1 = __shfl(b1, src, 64);
        float s2 = __shfl(b2, src, 64);
        if (s == 0) { s0 = 0.f; s1 = 0.f; s2 = 0.f; }
        #pragma unroll
        for (int k = 0; k < 32; ++k)
            y[k] += Htab[k][0]*s0 + Htab[k][1]*s1 + Htab[k][2]*s2;
    }
    __syncthreads();   // all tile reads (phase 1) complete before overwrite

    // ---- write y into tile (in place) ----
    #pragma unroll
    for (int u = 0; u < 8; ++u) {
        float4 o;
        o.x = y[4*u+0]; o.y = y[4*u+1]; o.z = y[4*u+2]; o.w = y[4*u+3];
        tile[r * ROWP4 + s * SEGP4 + u] = o;
    }
    __syncthreads();

    // ---- drain: contiguous SCALAR dword stores (R1 pattern; 1x WRITE_SIZE) ----
    const float* __restrict__ tf = reinterpret_cast<const float*>(tile);
    float* __restrict__ yb = reinterpret_cast<float*>(y4 + (size_t)row0 * F4ROW);
    #pragma unroll
    for (int it = 0; it < 32; ++it) {
        const int idx = it * NT + tid;      // 0..4095 floats, contiguous per wave
        const int rr  = idx >> 9;           // 512 floats per row
        const int g   = idx & 511;
        yb[idx] = tf[rr * (ROWP4*4) + (g >> 5) * (SEGP4*4) + (g & 31)];
    }
}

extern "C" void kernel_launch(void* const* d_in, const int* in_sizes, int n_in,
                              void* d_out, int out_size, void* d_ws, size_t ws_size,
                              hipStream_t stream) {
    const float4* x4 = (const float4*)d_in[0];
    const float*  w1 = (const float*)d_in[1];
    const float*  w2 = (const float*)d_in[2];
    float4* y4 = (float4*)d_out;

    const int nrows  = out_size / Wd;        // 131072
    const int blocks = nrows / TROWS;        // 16384
    iir_conv2d_kernel<<<blocks, NT, 0, stream>>>(x4, w1, w2, y4);
}